// Round 14
// baseline (145.168 us; speedup 1.0000x reference)
//
#include <hip/hip_runtime.h>

#define B_ 4
#define T_ 256
#define S_ 16384
#define E_ 256
#define H_ 8
#define D_ 32

typedef _Float16 f16;
typedef _Float16 f16x2 __attribute__((ext_vector_type(2)));
typedef _Float16 f16x4 __attribute__((ext_vector_type(4)));
typedef _Float16 f16x8 __attribute__((ext_vector_type(8)));
typedef float f32x4 __attribute__((ext_vector_type(4)));

typedef const __attribute__((address_space(1))) void* gas_t;
typedef __attribute__((address_space(3))) void* las_t;

#define FENCE() asm volatile("" ::: "memory")

__device__ __forceinline__ void gload_lds16(const void* g, void* l) {
    __builtin_amdgcn_global_load_lds((gas_t)g, (las_t)l, 16, 0, 0);
}

__device__ __forceinline__ f16x2 cvt_pk_f16(float a, float b) {
    return __builtin_bit_cast(f16x2, __builtin_amdgcn_cvt_pkrtz(a, b));
}

__device__ __forceinline__ f16x8 pack8(float4 a, float4 b) {
    f16x2 p0 = cvt_pk_f16(a.x, a.y), p1 = cvt_pk_f16(a.z, a.w);
    f16x2 p2 = cvt_pk_f16(b.x, b.y), p3 = cvt_pk_f16(b.z, b.w);
    return (f16x8){p0[0], p0[1], p1[0], p1[1], p2[0], p2[1], p3[0], p3[1]};
}

#define LOG2E 1.4426950408889634f

// ---------------- small-M GEMM (M=1024), f32 weights packed in-kernel ----------------
template <bool OUT16>
__device__ __forceinline__ void qproj32_body(
    f16* SMEM, const float* __restrict__ in, const float* __restrict__ w,
    const float* __restrict__ bias, void* __restrict__ outp, int bid, float oscale)
{
    f16 (*As)[264] = (f16(*)[264])SMEM;
    f16 (*Bs)[264] = (f16(*)[264])(SMEM + 32 * 264);
    int tid = threadIdx.x;
    int wq = tid >> 6, ln = tid & 63, g = ln >> 4, lc = ln & 15;
    int row0 = (bid & 31) * 32;
    int n0 = (bid >> 5) * 32;
    {
        int r = tid >> 3, q0 = (tid & 7) * 32;
        const float* ip = in + (size_t)(row0 + r) * 256 + q0;
        #pragma unroll
        for (int i = 0; i < 4; i++) {
            float4 v0 = *(const float4*)(ip + i * 8);
            float4 v1 = *(const float4*)(ip + i * 8 + 4);
            *(f16x8*)&As[r][q0 + i * 8] = pack8(v0, v1);
        }
        const float* wp = w + (size_t)(n0 + r) * 256 + q0;
        #pragma unroll
        for (int i = 0; i < 4; i++) {
            float4 v0 = *(const float4*)(wp + i * 8);
            float4 v1 = *(const float4*)(wp + i * 8 + 4);
            *(f16x8*)&Bs[r][q0 + i * 8] = pack8(v0, v1);
        }
    }
    __syncthreads();
    int mi = wq >> 1, ni = wq & 1;
    f32x4 acc = {0.f, 0.f, 0.f, 0.f};
    #pragma unroll
    for (int ks = 0; ks < 8; ks++) {
        f16x8 a = *(const f16x8*)&As[mi * 16 + lc][ks * 32 + g * 8];
        f16x8 bf = *(const f16x8*)&Bs[ni * 16 + lc][ks * 32 + g * 8];
        acc = __builtin_amdgcn_mfma_f32_16x16x32_f16(a, bf, acc, 0, 0, 0);
    }
    int n = n0 + ni * 16 + lc;
    float bv = bias[n];
    #pragma unroll
    for (int r = 0; r < 4; r++) {
        int row = row0 + mi * 16 + g * 4 + r;
        float val = (acc[r] + bv) * oscale;
        if (OUT16) ((f16*)outp)[(size_t)row * 256 + n] = (f16)val;
        else       ((float*)outp)[(size_t)row * 256 + n] = val;
    }
}

// ---------------- pre-kernel: weight cvt (Wk,Wv) + q-projection, one launch ----------------
__global__ __launch_bounds__(256) void pre_kernel(
    const float* __restrict__ Wk, const float* __restrict__ Wv,
    f16* __restrict__ Wk16, f16* __restrict__ Wv16,
    const float* __restrict__ query, const float* __restrict__ Wq,
    const float* __restrict__ bq, f16* __restrict__ q16, float qscale)
{
    __shared__ __align__(16) f16 SMEM[16896];
    int bx = blockIdx.x;
    if (bx < 128) {
        const float* src = bx < 64 ? Wk : Wv;
        f16* dst = bx < 64 ? Wk16 : Wv16;
        int i = ((bx & 63) * 256 + threadIdx.x) * 4;
        float4 v = *(const float4*)(src + i);
        f16x4 h = {(f16)v.x, (f16)v.y, (f16)v.z, (f16)v.w};
        *(f16x4*)(dst + i) = h;
    } else {
        qproj32_body<true>(SMEM, query, Wq, bq, q16, bx - 128, qscale);
    }
}

// ---------------- big projection GEMM v6 ----------------
// 512 threads = 8 waves; wave owns 32 n-cols (acc[4][2] = 32 AGPR). 64-row tile.
// A: ONE fully-coalesced burst (8 x f32x4/thread, linear 4KB/instr) -> full 64x256 f16
//    LDS tile [64][260] (bank-safe), one barrier total.
// B: wave-PRIVATE staging (wave wq gloads exactly rows wq*32..+31 it consumes) into a
//    single 16KB buffer -> NO barriers in the k-loop; per-step sync = vmcnt(0) (B only)
//    + lgkmcnt(0) before overwriting. Waves drift freely.
// LDS 49664 B; target regs <= 128 -> 4 waves/SIMD, 2 blocks/CU = 16 waves/CU.
template <int MODE>
__device__ __forceinline__ void proj_body6(
    char* SMEM, const float* __restrict__ in, const f16* __restrict__ w16,
    const float* __restrict__ bias, f16* __restrict__ out, int bx, float oscale)
{
    f16* As = (f16*)SMEM;                 // [64][260] = 33280 B
    f16* Bs = (f16*)(SMEM + 33280);       // [256][32] = 16384 B, wave-private rows
    int tid = threadIdx.x;
    int wq = tid >> 6, ln = tid & 63, g = ln >> 4, lc = ln & 15;
    int row0 = bx * 64;

    auto issueB = [&](int t) {
        int kb = t * 32;
        #pragma unroll
        for (int hh = 0; hh < 2; hh++) {
            int row = wq * 32 + hh * 16 + (ln >> 2);
            int sj = (ln & 3) ^ ((row >> 1) & 3);
            gload_lds16(w16 + (size_t)row * 256 + kb + sj * 8,
                        (char*)Bs + (wq * 32 + hh * 16) * 64);
        }
    };

    // prologue: B(0) + full A burst (coalesced 4KB per instruction)
    issueB(0);
    FENCE();
    const float* ab = in + (size_t)row0 * 256;
    f32x4 Ld[8];
    #pragma unroll
    for (int j = 0; j < 8; j++)
        Ld[j] = *(const f32x4*)(ab + (size_t)j * 2048 + tid * 4);
    asm volatile("s_waitcnt vmcnt(0)" ::: "memory");
    #pragma unroll
    for (int j = 0; j < 8; j++) {
        int row = j * 8 + wq;                    // all 64 lanes same row: 512B contiguous
        f16x4 h = {(f16)Ld[j][0], (f16)Ld[j][1], (f16)Ld[j][2], (f16)Ld[j][3]};
        *(f16x4*)&As[row * 260 + ln * 4] = h;
    }
    __syncthreads();

    f32x4 acc[4][2];
    #pragma unroll
    for (int i = 0; i < 4; i++) {
        acc[i][0] = (f32x4){0.f, 0.f, 0.f, 0.f};
        acc[i][1] = (f32x4){0.f, 0.f, 0.f, 0.f};
    }

    #pragma unroll
    for (int t = 0; t < 8; t++) {
        asm volatile("s_waitcnt vmcnt(0)" ::: "memory");   // B(t) landed (only vmem in flight)
        FENCE();
        f16x8 bf[2];
        #pragma unroll
        for (int ni = 0; ni < 2; ni++) {
            int n = wq * 32 + ni * 16 + lc;
            bf[ni] = *(const f16x8*)&Bs[n * 32 + ((g ^ ((n >> 1) & 3)) << 3)];
        }
        asm volatile("s_waitcnt lgkmcnt(0)" ::: "memory"); // bf in regs before overwrite
        FENCE();
        if (t + 1 < 8) { issueB(t + 1); FENCE(); }
        f16x8 af[4];
        #pragma unroll
        for (int mi = 0; mi < 4; mi++)
            af[mi] = *(const f16x8*)&As[(mi * 16 + lc) * 260 + t * 32 + g * 8];
        #pragma unroll
        for (int mi = 0; mi < 4; mi++) {
            acc[mi][0] = __builtin_amdgcn_mfma_f32_16x16x32_f16(af[mi], bf[0], acc[mi][0], 0, 0, 0);
            acc[mi][1] = __builtin_amdgcn_mfma_f32_16x16x32_f16(af[mi], bf[1], acc[mi][1], 0, 0, 0);
        }
    }

    if (MODE == 1) {
        // lane holds D[m = mi*16+g*4+r][n = wq*32+ni*16+lc]
        #pragma unroll
        for (int ni = 0; ni < 2; ni++) {
            int n = wq * 32 + ni * 16 + lc;
            float bv = bias[n];
            #pragma unroll
            for (int mi = 0; mi < 4; mi++) {
                #pragma unroll
                for (int r = 0; r < 4; r++) {
                    int row = row0 + mi * 16 + g * 4 + r;
                    out[(size_t)row * 256 + n] = (f16)((acc[mi][ni][r] + bv) * oscale);
                }
            }
        }
    } else {
        // transpose via LDS overlay TR[256][68]
        f16* TR = (f16*)SMEM;
        __syncthreads();   // all waves done with As/Bs
        #pragma unroll
        for (int ni = 0; ni < 2; ni++) {
            int n = wq * 32 + ni * 16 + lc;
            float bv = bias[n];
            #pragma unroll
            for (int mi = 0; mi < 4; mi++) {
                f16x4 hv;
                #pragma unroll
                for (int r = 0; r < 4; r++) hv[r] = (f16)((acc[mi][ni][r] + bv) * oscale);
                *(f16x4*)&TR[n * 68 + mi * 16 + g * 4] = hv;
            }
        }
        __syncthreads();
        int bb = row0 >> 14, sbase = row0 & 16383;
        #pragma unroll
        for (int p = 0; p < 2; p++) {
            int n = p * 128 + wq * 16 + (ln >> 2);
            int sc = (ln & 3) * 16;
            f16x8 v0 = *(const f16x8*)&TR[n * 68 + sc];
            f16x8 v1 = *(const f16x8*)&TR[n * 68 + sc + 8];
            f16* op = out + ((size_t)(bb * 256 + n)) * 16384 + sbase + sc;
            *(f16x8*)op = v0;
            *(f16x8*)(op + 8) = v1;
        }
    }
}

__global__ __launch_bounds__(512, 4) void proj_kv6(
    const float* __restrict__ key, const float* __restrict__ value,
    const f16* __restrict__ Wk16, const f16* __restrict__ Wv16,
    const float* __restrict__ bk, const float* __restrict__ bv,
    f16* __restrict__ k16, f16* __restrict__ v16T)
{
    __shared__ __align__(16) char SMEM[49664];
    int bx = blockIdx.x;
    if (bx < 1024) proj_body6<1>(SMEM, key,   Wk16, bk, k16,  bx, 1.0f);
    else           proj_body6<2>(SMEM, value, Wv16, bv, v16T, bx - 1024, 1.0f);
}

// ---------------- out-projection (M=1024, f32 weights, f32 out) ----------------
__global__ __launch_bounds__(256, 4) void out_proj(
    const float* __restrict__ in, const float* __restrict__ w,
    const float* __restrict__ bias, float* __restrict__ outp)
{
    __shared__ __align__(16) f16 SMEM[16896];
    qproj32_body<false>(SMEM, in, w, bias, outp, blockIdx.x + blockIdx.y * 32, 1.0f);
}

// ---------------- attention kernel (fixed-max softmax) ----------------
__global__ __launch_bounds__(1024, 4) void attn_kernel(
    const f16* __restrict__ q16,   // [B,T,E] (qscale*log2e folded in)
    const f16* __restrict__ k16,   // [B,S,E]
    const f16* __restrict__ v16T,  // [B,E,S] transposed
    const float* __restrict__ mask,// [B,T,S]
    const float* __restrict__ scal,// [8]
    float* __restrict__ partO, float* __restrict__ partL)
{
    constexpr int ITERS = 16;
    __shared__ __align__(16) f16 KT[3][32 * 256];
    __shared__ __align__(16) f16 VT[3][256 * 32];
    __shared__ __align__(16) float MT[3][128 * 32];

    int raw = blockIdx.x;
    int th = raw >> 7, b = (raw >> 5) & 3, ck = raw & 31;
    int tid = threadIdx.x;
    int wv = tid >> 6;
    int h = wv & 7, tsub = wv >> 3;
    int ln = tid & 63, g = ln >> 4, lc = ln & 15;
    int t0 = th * 128, s0 = ck * 512;

    float sc_h = scal[h] * LOG2E;
    float negfix = -(sc_h + 4.0f);

    f16x8 qf[4];
    #pragma unroll
    for (int tl = 0; tl < 4; tl++) {
        const f16* qp = q16 + (size_t)(b * T_ + t0 + tsub * 64 + tl * 16 + lc) * E_ + h * 32 + g * 8;
        qf[tl] = *(const f16x8*)qp;
    }

    f32x4 oac[4][2];
    float l_part[4];
    #pragma unroll
    for (int tl = 0; tl < 4; tl++) {
        oac[tl][0] = (f32x4){0.f, 0.f, 0.f, 0.f};
        oac[tl][1] = (f32x4){0.f, 0.f, 0.f, 0.f};
        l_part[tl] = 0.f;
    }

    auto stage = [&](int it, int bufi) {
        int sg0 = s0 + it * 32;
        {
            int sl = wv * 2 + (ln >> 5);
            int slot = (sl ^ (sl >> 3)) & 7;
            int jc = (ln & 31) ^ slot;
            gload_lds16(k16 + (size_t)(b * S_ + sg0 + sl) * E_ + jc * 8,
                        (char*)&KT[bufi][0] + wv * 1024);
        }
        {
            int dl = wv * 16 + (ln >> 2);
            int srcj = (ln & 3) ^ ((dl >> 1) & 3);
            gload_lds16(v16T + (size_t)(b * E_ + dl) * S_ + sg0 + srcj * 8,
                        (char*)&VT[bufi][0] + wv * 1024);
        }
        {
            int r = ln >> 3;
            int sj = (ln & 7) ^ r;
            gload_lds16(mask + (size_t)(b * T_ + t0 + wv * 8 + r) * S_ + sg0 + sj * 4,
                        (char*)&MT[bufi][0] + wv * 1024);
        }
    };

    stage(0, 0);
    stage(1, 1);

    f32x4 zero4 = {0.f, 0.f, 0.f, 0.f};
    int ib = 0;

    #pragma unroll 1
    for (int it = 0; it < ITERS; it++) {
        if (it + 1 < ITERS) { asm volatile("s_waitcnt vmcnt(3)" ::: "memory"); }
        else                { asm volatile("s_waitcnt vmcnt(0)" ::: "memory"); }
        __builtin_amdgcn_s_barrier();
        FENCE();
        if (it + 2 < ITERS) {
            int wb = ib + 2; if (wb >= 3) wb -= 3;
            stage(it + 2, wb);
        }

        f16x8 kb[2];
        #pragma unroll
        for (int si = 0; si < 2; si++) {
            int sl = si * 16 + lc;
            int slot = (sl ^ (sl >> 3)) & 7;
            int j = (h * 4 + g) ^ slot;
            kb[si] = *(const f16x8*)((char*)&KT[ib][0] + sl * 512 + j * 16);
        }
        f16x4 va[2][2];
        #pragma unroll
        for (int si = 0; si < 2; si++) {
            #pragma unroll
            for (int ni = 0; ni < 2; ni++) {
                int d = h * 32 + ni * 16 + lc;
                int u = (si * 2 + (g >> 1)) ^ ((d >> 1) & 3);
                va[si][ni] = *(const f16x4*)((char*)&VT[ib][0] + d * 64 + u * 16 + (g & 1) * 8);
            }
        }

        #pragma unroll
        for (int tl = 0; tl < 4; tl++) {
            int t = tsub * 64 + tl * 16 + lc;
            const float4 mf0 = *(const float4*)((char*)&MT[ib][0] + t * 128 + (((g    ) ^ (t & 7)) << 4));
            const float4 mf1 = *(const float4*)((char*)&MT[ib][0] + t * 128 + (((4 + g) ^ (t & 7)) << 4));
            f32x4 st0 = __builtin_amdgcn_mfma_f32_16x16x32_f16(kb[0], qf[tl], zero4, 0, 0, 0);
            f32x4 st1 = __builtin_amdgcn_mfma_f32_16x16x32_f16(kb[1], qf[tl], zero4, 0, 0, 0);
            float p0 = __builtin_amdgcn_exp2f(st0[0] + __builtin_fmaf(mf0.x, sc_h, negfix));
            float p1 = __builtin_amdgcn_exp2f(st0[1] + __builtin_fmaf(mf0.y, sc_h, negfix));
            float p2 = __builtin_amdgcn_exp2f(st0[2] + __builtin_fmaf(mf0.z, sc_h, negfix));
            float p3 = __builtin_amdgcn_exp2f(st0[3] + __builtin_fmaf(mf0.w, sc_h, negfix));
            float p4 = __builtin_amdgcn_exp2f(st1[0] + __builtin_fmaf(mf1.x, sc_h, negfix));
            float p5 = __builtin_amdgcn_exp2f(st1[1] + __builtin_fmaf(mf1.y, sc_h, negfix));
            float p6 = __builtin_amdgcn_exp2f(st1[2] + __builtin_fmaf(mf1.z, sc_h, negfix));
            float p7 = __builtin_amdgcn_exp2f(st1[3] + __builtin_fmaf(mf1.w, sc_h, negfix));
            l_part[tl] += ((p0 + p1) + (p2 + p3)) + ((p4 + p5) + (p6 + p7));
            f16x2 c01 = cvt_pk_f16(p0, p1);
            f16x2 c23 = cvt_pk_f16(p2, p3);
            f16x2 c45 = cvt_pk_f16(p4, p5);
            f16x2 c67 = cvt_pk_f16(p6, p7);
            f16x4 pb0 = {c01[0], c01[1], c23[0], c23[1]};
            f16x4 pb1 = {c45[0], c45[1], c67[0], c67[1]};
            oac[tl][0] = __builtin_amdgcn_mfma_f32_16x16x16f16(va[0][0], pb0, oac[tl][0], 0, 0, 0);
            oac[tl][0] = __builtin_amdgcn_mfma_f32_16x16x16f16(va[1][0], pb1, oac[tl][0], 0, 0, 0);
            oac[tl][1] = __builtin_amdgcn_mfma_f32_16x16x16f16(va[0][1], pb0, oac[tl][1], 0, 0, 0);
            oac[tl][1] = __builtin_amdgcn_mfma_f32_16x16x16f16(va[1][1], pb1, oac[tl][1], 0, 0, 0);
        }
        ib++; if (ib >= 3) ib -= 3;
    }

    #pragma unroll
    for (int tl = 0; tl < 4; tl++) {
        float lv = l_part[tl];
        lv += __shfl_xor(lv, 16, 64);
        lv += __shfl_xor(lv, 32, 64);
        l_part[tl] = lv;
    }
    float* po = partO + (size_t)raw * 128 * 256;
    #pragma unroll
    for (int tl = 0; tl < 4; tl++) {
        #pragma unroll
        for (int ni = 0; ni < 2; ni++) {
            float4 o4 = {oac[tl][ni][0], oac[tl][ni][1], oac[tl][ni][2], oac[tl][ni][3]};
            *(float4*)(po + (size_t)(tsub * 64 + tl * 16 + lc) * 256 + h * 32 + ni * 16 + g * 4) = o4;
        }
    }
    if (g == 0) {
        float* pl = partL + (size_t)raw * 128 * 8;
        #pragma unroll
        for (int tl = 0; tl < 4; tl++) {
            int trow = tsub * 64 + tl * 16 + lc;
            pl[trow * 8 + h] = l_part[tl];
        }
    }
}

// ---------------- split-S combine (pure sum) ----------------
__global__ __launch_bounds__(256) void combine_kernel(
    const float* __restrict__ partO, const float* __restrict__ partL,
    float* __restrict__ attnO)
{
    int bid = blockIdx.x;
    int b = bid >> 8, t = bid & 255;
    int th = t >> 7, tl = t & 127;
    int tid = threadIdx.x;
    __shared__ float sl[32][8];
    {
        int ck = tid >> 3, hh = tid & 7;
        size_t blk = (size_t)(th * 128 + b * 32 + ck);
        sl[ck][hh] = partL[blk * 1024 + tl * 8 + hh];
    }
    __syncthreads();
    int h = tid >> 5;
    float L = 0.f;
    #pragma unroll 8
    for (int ck = 0; ck < 32; ck++) L += sl[ck][h];
    float acc = 0.f;
    #pragma unroll 4
    for (int ck = 0; ck < 32; ck++) {
        size_t blk = (size_t)(th * 128 + b * 32 + ck);
        acc += partO[blk * 32768 + (size_t)tl * 256 + tid];
    }
    attnO[(size_t)bid * 256 + tid] = acc / L;
}

extern "C" void kernel_launch(void* const* d_in, const int* in_sizes, int n_in,
                              void* d_out, int out_size, void* d_ws, size_t ws_size,
                              hipStream_t stream) {
    (void)in_sizes; (void)n_in; (void)out_size; (void)ws_size;
    const float* query = (const float*)d_in[0];
    const float* key   = (const float*)d_in[1];
    const float* value = (const float*)d_in[2];
    const float* mask  = (const float*)d_in[3];
    const float* Wq = (const float*)d_in[4];
    const float* bq = (const float*)d_in[5];
    const float* Wk = (const float*)d_in[6];
    const float* bk = (const float*)d_in[7];
    const float* Wv = (const float*)d_in[8];
    const float* bv = (const float*)d_in[9];
    const float* Wo = (const float*)d_in[10];
    const float* bo = (const float*)d_in[11];
    const float* scal = (const float*)d_in[12];

    char* ws = (char*)d_ws;
    f16* Wk16 = (f16*)(ws + 0);
    f16* Wv16 = (f16*)(ws + (1 << 17));
    f16* q16  = (f16*)(ws + (4 << 17));        // 512KB
    float* attnO = (float*)(ws + 1048576);     // 1MB
    f16* k16  = (f16*)(ws + 2097152);          // 32MB, [B,S,E]
    f16* v16T = (f16*)(ws + 35651584);         // 32MB, [B,E,S]
    float* partO = (float*)(ws + 69206016);    // 32MB
    float* partL = (float*)(ws + 103809024);   // 1MB

    const float qscale = 0.17677669529663687f * LOG2E; // 1/sqrt(32) * log2(e)
    pre_kernel<<<384, 256, 0, stream>>>(Wk, Wv, Wk16, Wv16, query, Wq, bq, q16, qscale);

    proj_kv6<<<2048, 512, 0, stream>>>(key, value, Wk16, Wv16, bk, bv, k16, v16T);

    attn_kernel<<<256, 1024, 0, stream>>>(q16, k16, v16T, mask, scal, partO, partL);
    combine_kernel<<<1024, 256, 0, stream>>>(partO, partL, attnO);

    out_proj<<<dim3(32, 8), 256, 0, stream>>>(attnO, Wo, bo, (float*)d_out);
}

// Round 15
// 126.269 us; speedup vs baseline: 1.1497x; 1.1497x over previous
//
#include <hip/hip_runtime.h>

#define B_ 4
#define T_ 256
#define S_ 16384
#define E_ 256
#define H_ 8
#define D_ 32

typedef _Float16 f16;
typedef _Float16 f16x2 __attribute__((ext_vector_type(2)));
typedef _Float16 f16x4 __attribute__((ext_vector_type(4)));
typedef _Float16 f16x8 __attribute__((ext_vector_type(8)));
typedef float f32x4 __attribute__((ext_vector_type(4)));

typedef const __attribute__((address_space(1))) void* gas_t;
typedef __attribute__((address_space(3))) void* las_t;

#define FENCE() asm volatile("" ::: "memory")

__device__ __forceinline__ void gload_lds16(const void* g, void* l) {
    __builtin_amdgcn_global_load_lds((gas_t)g, (las_t)l, 16, 0, 0);
}

__device__ __forceinline__ f16x2 cvt_pk_f16(float a, float b) {
    return __builtin_bit_cast(f16x2, __builtin_amdgcn_cvt_pkrtz(a, b));
}

__device__ __forceinline__ f16x8 pack8(float4 a, float4 b) {
    f16x2 p0 = cvt_pk_f16(a.x, a.y), p1 = cvt_pk_f16(a.z, a.w);
    f16x2 p2 = cvt_pk_f16(b.x, b.y), p3 = cvt_pk_f16(b.z, b.w);
    return (f16x8){p0[0], p0[1], p1[0], p1[1], p2[0], p2[1], p3[0], p3[1]};
}

__device__ __forceinline__ f16x8 pack8v(f32x4 a, f32x4 b) {
    f16x2 p0 = cvt_pk_f16(a[0], a[1]), p1 = cvt_pk_f16(a[2], a[3]);
    f16x2 p2 = cvt_pk_f16(b[0], b[1]), p3 = cvt_pk_f16(b[2], b[3]);
    return (f16x8){p0[0], p0[1], p1[0], p1[1], p2[0], p2[1], p3[0], p3[1]};
}

#define LOG2E 1.4426950408889634f

// ---------------- weight f32 -> f16 convert (Wk, Wv only) ----------------
__global__ void cvt_w2_kernel(const float* __restrict__ wa, const float* __restrict__ wb,
                              f16* __restrict__ oa, f16* __restrict__ ob) {
    int m = blockIdx.y;
    const float* src = m == 0 ? wa : wb;
    f16* dst = m == 0 ? oa : ob;
    int i = (blockIdx.x * 256 + threadIdx.x) * 4;
    float4 v = *(const float4*)(src + i);
    f16x4 h = {(f16)v.x, (f16)v.y, (f16)v.z, (f16)v.w};
    *(f16x4*)(dst + i) = h;
}

// ---------------- small-M GEMM (M=1024), f32 weights packed in-kernel ----------------
template <bool OUT16>
__device__ __forceinline__ void qproj32_body(
    f16* SMEM, const float* __restrict__ in, const float* __restrict__ w,
    const float* __restrict__ bias, void* __restrict__ outp, int bid, float oscale)
{
    f16 (*As)[264] = (f16(*)[264])SMEM;
    f16 (*Bs)[264] = (f16(*)[264])(SMEM + 32 * 264);
    int tid = threadIdx.x;
    int wq = tid >> 6, ln = tid & 63, g = ln >> 4, lc = ln & 15;
    int row0 = (bid & 31) * 32;
    int n0 = (bid >> 5) * 32;
    {
        int r = tid >> 3, q0 = (tid & 7) * 32;
        const float* ip = in + (size_t)(row0 + r) * 256 + q0;
        #pragma unroll
        for (int i = 0; i < 4; i++) {
            float4 v0 = *(const float4*)(ip + i * 8);
            float4 v1 = *(const float4*)(ip + i * 8 + 4);
            *(f16x8*)&As[r][q0 + i * 8] = pack8(v0, v1);
        }
        const float* wp = w + (size_t)(n0 + r) * 256 + q0;
        #pragma unroll
        for (int i = 0; i < 4; i++) {
            float4 v0 = *(const float4*)(wp + i * 8);
            float4 v1 = *(const float4*)(wp + i * 8 + 4);
            *(f16x8*)&Bs[r][q0 + i * 8] = pack8(v0, v1);
        }
    }
    __syncthreads();
    int mi = wq >> 1, ni = wq & 1;
    f32x4 acc = {0.f, 0.f, 0.f, 0.f};
    #pragma unroll
    for (int ks = 0; ks < 8; ks++) {
        f16x8 a = *(const f16x8*)&As[mi * 16 + lc][ks * 32 + g * 8];
        f16x8 bf = *(const f16x8*)&Bs[ni * 16 + lc][ks * 32 + g * 8];
        acc = __builtin_amdgcn_mfma_f32_16x16x32_f16(a, bf, acc, 0, 0, 0);
    }
    int n = n0 + ni * 16 + lc;
    float bv = bias[n];
    #pragma unroll
    for (int r = 0; r < 4; r++) {
        int row = row0 + mi * 16 + g * 4 + r;
        float val = (acc[r] + bv) * oscale;
        if (OUT16) ((f16*)outp)[(size_t)row * 256 + n] = (f16)val;
        else       ((float*)outp)[(size_t)row * 256 + n] = val;
    }
}

// ---------------- big projection GEMM v7: all-gload_lds, 3-buffer, depth-2 ----------------
// 256 threads = 4 waves, 64-row tile, 8 k-steps of 32.
// A staged as RAW F32 via gload_lds (f16 cvt after ds_read): 3 bufs x 8KB, 16B-slot
//   XOR-swizzled source (rule: linear dest + inverse-swz source + swz read).
// B staged via gload_lds from f16 weights: 3 bufs x 16KB, round-13 swizzle.
// Uniform staging: stage(t) = 6 gloads/wave; per step: vmcnt(6) [stage(t) done,
//   stage(t+1) in flight] -> barrier -> issue stage(t+2). Depth 2 on BOTH streams.
// LDS 73728 B -> 2 blocks/CU. MODE 1: f16 linear out; MODE 2: transposed v16T.
template <int MODE>
__device__ __forceinline__ void proj_body7(
    char* SMEM, const float* __restrict__ in, const f16* __restrict__ w16,
    const float* __restrict__ bias, f16* __restrict__ out, int bx, float oscale)
{
    char* Ab = SMEM;              // 3 x 8192: f32 tile [64 rows][128B], swizzled slots
    char* Bb = SMEM + 24576;      // 3 x 16384: f16 [256][32], swizzled
    int tid = threadIdx.x;
    int wv = tid >> 6, ln = tid & 63, g = ln >> 4, lc = ln & 15;
    int row0 = bx * 64;

    auto stage = [&](int t, int buf) {
        // B: 4 chunks of 1KB per wave (identical to round 13)
        #pragma unroll
        for (int c4 = 0; c4 < 4; c4++) {
            int cc = wv * 4 + c4;
            int row = cc * 16 + (ln >> 2);
            int sj = (ln & 3) ^ ((row >> 1) & 3);
            gload_lds16(w16 + (size_t)row * 256 + t * 32 + sj * 8,
                        Bb + buf * 16384 + cc * 1024);
        }
        // A: 2 chunks of 1KB per wave; chunk q covers 8 rows x 128B (32 f32)
        #pragma unroll
        for (int q2 = 0; q2 < 2; q2++) {
            int q = wv * 2 + q2;
            int rl = ln >> 3;                       // row within chunk = global row&7
            int ssl = (ln & 7) ^ rl;                // pre-swizzled 16B source slot
            gload_lds16(in + (size_t)(row0 + q * 8 + rl) * 256 + t * 32 + ssl * 4,
                        Ab + buf * 8192 + q * 1024);
        }
    };

    f32x4 acc[4][4];
    #pragma unroll
    for (int i = 0; i < 4; i++)
        #pragma unroll
        for (int j = 0; j < 4; j++) acc[i][j] = (f32x4){0.f, 0.f, 0.f, 0.f};

    stage(0, 0);
    stage(1, 1);

    int ib = 0;
    #pragma unroll 1
    for (int t = 0; t < 8; t++) {
        if (t < 7) { asm volatile("s_waitcnt vmcnt(6)" ::: "memory"); }
        else       { asm volatile("s_waitcnt vmcnt(0)" ::: "memory"); }
        __builtin_amdgcn_s_barrier();
        FENCE();
        if (t + 2 < 8) {
            int wb = ib + 2; if (wb >= 3) wb -= 3;
            stage(t + 2, wb);
        }

        f16x8 af[4], bf[4];
        #pragma unroll
        for (int mi = 0; mi < 4; mi++) {
            int row = mi * 16 + lc;
            int s0 = (2 * g) ^ (row & 7);
            int s1 = (2 * g + 1) ^ (row & 7);
            f32x4 lo = *(const f32x4*)(Ab + ib * 8192 + row * 128 + s0 * 16);
            f32x4 hi = *(const f32x4*)(Ab + ib * 8192 + row * 128 + s1 * 16);
            af[mi] = pack8v(lo, hi);
        }
        #pragma unroll
        for (int ni = 0; ni < 4; ni++) {
            int n = wv * 64 + ni * 16 + lc;
            bf[ni] = *(const f16x8*)(Bb + ib * 16384 + n * 64 + ((g ^ ((n >> 1) & 3)) << 4));
        }
        #pragma unroll
        for (int mi = 0; mi < 4; mi++)
            #pragma unroll
            for (int ni = 0; ni < 4; ni++)
                acc[mi][ni] = __builtin_amdgcn_mfma_f32_16x16x32_f16(af[mi], bf[ni], acc[mi][ni], 0, 0, 0);
        ib++; if (ib >= 3) ib -= 3;
    }

    if (MODE == 1) {
        #pragma unroll
        for (int ni = 0; ni < 4; ni++) {
            int n = wv * 64 + ni * 16 + lc;
            float bv = bias[n];
            #pragma unroll
            for (int mi = 0; mi < 4; mi++) {
                #pragma unroll
                for (int r = 0; r < 4; r++) {
                    int row = row0 + mi * 16 + g * 4 + r;
                    out[(size_t)row * 256 + n] = (f16)((acc[mi][ni][r] + bv) * oscale);
                }
            }
        }
    } else {
        f16* TR = (f16*)SMEM;   // 256*68*2 = 34816 B overlay
        __syncthreads();
        #pragma unroll
        for (int ni = 0; ni < 4; ni++) {
            int n = wv * 64 + ni * 16 + lc;
            float bv = bias[n];
            #pragma unroll
            for (int mi = 0; mi < 4; mi++) {
                f16x4 hv;
                #pragma unroll
                for (int r = 0; r < 4; r++) hv[r] = (f16)((acc[mi][ni][r] + bv) * oscale);
                *(f16x4*)&TR[n * 68 + mi * 16 + g * 4] = hv;
            }
        }
        __syncthreads();
        int bb = row0 >> 14, sbase = row0 & 16383;
        #pragma unroll
        for (int p = 0; p < 4; p++) {
            int n = p * 64 + wv * 16 + (ln >> 2);
            int sc = (ln & 3) * 16;
            f16x8 v0 = *(const f16x8*)&TR[n * 68 + sc];
            f16x8 v1 = *(const f16x8*)&TR[n * 68 + sc + 8];
            f16* op = out + ((size_t)(bb * 256 + n)) * 16384 + sbase + sc;
            *(f16x8*)op = v0;
            *(f16x8*)(op + 8) = v1;
        }
    }
}

// ---------------- fused q/k/v projections: one launch, 2304 blocks ----------------
__global__ __launch_bounds__(256, 2) void proj_fused7(
    const float* __restrict__ query, const float* __restrict__ key, const float* __restrict__ value,
    const float* __restrict__ Wq, const f16* __restrict__ Wk16, const f16* __restrict__ Wv16,
    const float* __restrict__ bq, const float* __restrict__ bk, const float* __restrict__ bv,
    f16* __restrict__ q16, f16* __restrict__ k16, f16* __restrict__ v16T, float qscale)
{
    __shared__ __align__(16) char SMEM[73728];
    int bx = blockIdx.x;
    if (bx < 1024) {
        proj_body7<1>(SMEM, key, Wk16, bk, k16, bx, 1.0f);
    } else if (bx < 2048) {
        proj_body7<2>(SMEM, value, Wv16, bv, v16T, bx - 1024, 1.0f);
    } else {
        qproj32_body<true>((f16*)SMEM, query, Wq, bq, q16, bx - 2048, qscale);
    }
}

// ---------------- out-projection (M=1024, f32 weights, f32 out) ----------------
__global__ __launch_bounds__(256, 4) void out_proj(
    const float* __restrict__ in, const float* __restrict__ w,
    const float* __restrict__ bias, float* __restrict__ outp)
{
    __shared__ __align__(16) f16 SMEM[16896];
    qproj32_body<false>(SMEM, in, w, bias, outp, blockIdx.x + blockIdx.y * 32, 1.0f);
}

// ---------------- attention kernel (fixed-max softmax) ----------------
__global__ __launch_bounds__(1024, 4) void attn_kernel(
    const f16* __restrict__ q16,   // [B,T,E] (qscale*log2e folded in)
    const f16* __restrict__ k16,   // [B,S,E]
    const f16* __restrict__ v16T,  // [B,E,S] transposed
    const float* __restrict__ mask,// [B,T,S]
    const float* __restrict__ scal,// [8]
    float* __restrict__ partO, float* __restrict__ partL)
{
    constexpr int ITERS = 16;
    __shared__ __align__(16) f16 KT[3][32 * 256];
    __shared__ __align__(16) f16 VT[3][256 * 32];
    __shared__ __align__(16) float MT[3][128 * 32];

    int raw = blockIdx.x;
    int th = raw >> 7, b = (raw >> 5) & 3, ck = raw & 31;
    int tid = threadIdx.x;
    int wv = tid >> 6;
    int h = wv & 7, tsub = wv >> 3;
    int ln = tid & 63, g = ln >> 4, lc = ln & 15;
    int t0 = th * 128, s0 = ck * 512;

    float sc_h = scal[h] * LOG2E;
    float negfix = -(sc_h + 4.0f);

    f16x8 qf[4];
    #pragma unroll
    for (int tl = 0; tl < 4; tl++) {
        const f16* qp = q16 + (size_t)(b * T_ + t0 + tsub * 64 + tl * 16 + lc) * E_ + h * 32 + g * 8;
        qf[tl] = *(const f16x8*)qp;
    }

    f32x4 oac[4][2];
    float l_part[4];
    #pragma unroll
    for (int tl = 0; tl < 4; tl++) {
        oac[tl][0] = (f32x4){0.f, 0.f, 0.f, 0.f};
        oac[tl][1] = (f32x4){0.f, 0.f, 0.f, 0.f};
        l_part[tl] = 0.f;
    }

    auto stage = [&](int it, int bufi) {
        int sg0 = s0 + it * 32;
        {
            int sl = wv * 2 + (ln >> 5);
            int slot = (sl ^ (sl >> 3)) & 7;
            int jc = (ln & 31) ^ slot;
            gload_lds16(k16 + (size_t)(b * S_ + sg0 + sl) * E_ + jc * 8,
                        (char*)&KT[bufi][0] + wv * 1024);
        }
        {
            int dl = wv * 16 + (ln >> 2);
            int srcj = (ln & 3) ^ ((dl >> 1) & 3);
            gload_lds16(v16T + (size_t)(b * E_ + dl) * S_ + sg0 + srcj * 8,
                        (char*)&VT[bufi][0] + wv * 1024);
        }
        {
            int r = ln >> 3;
            int sj = (ln & 7) ^ r;
            gload_lds16(mask + (size_t)(b * T_ + t0 + wv * 8 + r) * S_ + sg0 + sj * 4,
                        (char*)&MT[bufi][0] + wv * 1024);
        }
    };

    stage(0, 0);
    stage(1, 1);

    f32x4 zero4 = {0.f, 0.f, 0.f, 0.f};
    int ib = 0;

    #pragma unroll 1
    for (int it = 0; it < ITERS; it++) {
        if (it + 1 < ITERS) { asm volatile("s_waitcnt vmcnt(3)" ::: "memory"); }
        else                { asm volatile("s_waitcnt vmcnt(0)" ::: "memory"); }
        __builtin_amdgcn_s_barrier();
        FENCE();
        if (it + 2 < ITERS) {
            int wb = ib + 2; if (wb >= 3) wb -= 3;
            stage(it + 2, wb);
        }

        f16x8 kb[2];
        #pragma unroll
        for (int si = 0; si < 2; si++) {
            int sl = si * 16 + lc;
            int slot = (sl ^ (sl >> 3)) & 7;
            int j = (h * 4 + g) ^ slot;
            kb[si] = *(const f16x8*)((char*)&KT[ib][0] + sl * 512 + j * 16);
        }
        f16x4 va[2][2];
        #pragma unroll
        for (int si = 0; si < 2; si++) {
            #pragma unroll
            for (int ni = 0; ni < 2; ni++) {
                int d = h * 32 + ni * 16 + lc;
                int u = (si * 2 + (g >> 1)) ^ ((d >> 1) & 3);
                va[si][ni] = *(const f16x4*)((char*)&VT[ib][0] + d * 64 + u * 16 + (g & 1) * 8);
            }
        }

        #pragma unroll
        for (int tl = 0; tl < 4; tl++) {
            int t = tsub * 64 + tl * 16 + lc;
            const float4 mf0 = *(const float4*)((char*)&MT[ib][0] + t * 128 + (((g    ) ^ (t & 7)) << 4));
            const float4 mf1 = *(const float4*)((char*)&MT[ib][0] + t * 128 + (((4 + g) ^ (t & 7)) << 4));
            f32x4 st0 = __builtin_amdgcn_mfma_f32_16x16x32_f16(kb[0], qf[tl], zero4, 0, 0, 0);
            f32x4 st1 = __builtin_amdgcn_mfma_f32_16x16x32_f16(kb[1], qf[tl], zero4, 0, 0, 0);
            float p0 = __builtin_amdgcn_exp2f(st0[0] + __builtin_fmaf(mf0.x, sc_h, negfix));
            float p1 = __builtin_amdgcn_exp2f(st0[1] + __builtin_fmaf(mf0.y, sc_h, negfix));
            float p2 = __builtin_amdgcn_exp2f(st0[2] + __builtin_fmaf(mf0.z, sc_h, negfix));
            float p3 = __builtin_amdgcn_exp2f(st0[3] + __builtin_fmaf(mf0.w, sc_h, negfix));
            float p4 = __builtin_amdgcn_exp2f(st1[0] + __builtin_fmaf(mf1.x, sc_h, negfix));
            float p5 = __builtin_amdgcn_exp2f(st1[1] + __builtin_fmaf(mf1.y, sc_h, negfix));
            float p6 = __builtin_amdgcn_exp2f(st1[2] + __builtin_fmaf(mf1.z, sc_h, negfix));
            float p7 = __builtin_amdgcn_exp2f(st1[3] + __builtin_fmaf(mf1.w, sc_h, negfix));
            l_part[tl] += ((p0 + p1) + (p2 + p3)) + ((p4 + p5) + (p6 + p7));
            f16x2 c01 = cvt_pk_f16(p0, p1);
            f16x2 c23 = cvt_pk_f16(p2, p3);
            f16x2 c45 = cvt_pk_f16(p4, p5);
            f16x2 c67 = cvt_pk_f16(p6, p7);
            f16x4 pb0 = {c01[0], c01[1], c23[0], c23[1]};
            f16x4 pb1 = {c45[0], c45[1], c67[0], c67[1]};
            oac[tl][0] = __builtin_amdgcn_mfma_f32_16x16x16f16(va[0][0], pb0, oac[tl][0], 0, 0, 0);
            oac[tl][0] = __builtin_amdgcn_mfma_f32_16x16x16f16(va[1][0], pb1, oac[tl][0], 0, 0, 0);
            oac[tl][1] = __builtin_amdgcn_mfma_f32_16x16x16f16(va[0][1], pb0, oac[tl][1], 0, 0, 0);
            oac[tl][1] = __builtin_amdgcn_mfma_f32_16x16x16f16(va[1][1], pb1, oac[tl][1], 0, 0, 0);
        }
        ib++; if (ib >= 3) ib -= 3;
    }

    #pragma unroll
    for (int tl = 0; tl < 4; tl++) {
        float lv = l_part[tl];
        lv += __shfl_xor(lv, 16, 64);
        lv += __shfl_xor(lv, 32, 64);
        l_part[tl] = lv;
    }
    float* po = partO + (size_t)raw * 128 * 256;
    #pragma unroll
    for (int tl = 0; tl < 4; tl++) {
        #pragma unroll
        for (int ni = 0; ni < 2; ni++) {
            float4 o4 = {oac[tl][ni][0], oac[tl][ni][1], oac[tl][ni][2], oac[tl][ni][3]};
            *(float4*)(po + (size_t)(tsub * 64 + tl * 16 + lc) * 256 + h * 32 + ni * 16 + g * 4) = o4;
        }
    }
    if (g == 0) {
        float* pl = partL + (size_t)raw * 128 * 8;
        #pragma unroll
        for (int tl = 0; tl < 4; tl++) {
            int trow = tsub * 64 + tl * 16 + lc;
            pl[trow * 8 + h] = l_part[tl];
        }
    }
}

// ---------------- split-S combine (pure sum) ----------------
__global__ __launch_bounds__(256) void combine_kernel(
    const float* __restrict__ partO, const float* __restrict__ partL,
    float* __restrict__ attnO)
{
    int bid = blockIdx.x;
    int b = bid >> 8, t = bid & 255;
    int th = t >> 7, tl = t & 127;
    int tid = threadIdx.x;
    __shared__ float sl[32][8];
    {
        int ck = tid >> 3, hh = tid & 7;
        size_t blk = (size_t)(th * 128 + b * 32 + ck);
        sl[ck][hh] = partL[blk * 1024 + tl * 8 + hh];
    }
    __syncthreads();
    int h = tid >> 5;
    float L = 0.f;
    #pragma unroll 8
    for (int ck = 0; ck < 32; ck++) L += sl[ck][h];
    float acc = 0.f;
    #pragma unroll 4
    for (int ck = 0; ck < 32; ck++) {
        size_t blk = (size_t)(th * 128 + b * 32 + ck);
        acc += partO[blk * 32768 + (size_t)tl * 256 + tid];
    }
    attnO[(size_t)bid * 256 + tid] = acc / L;
}

extern "C" void kernel_launch(void* const* d_in, const int* in_sizes, int n_in,
                              void* d_out, int out_size, void* d_ws, size_t ws_size,
                              hipStream_t stream) {
    (void)in_sizes; (void)n_in; (void)out_size; (void)ws_size;
    const float* query = (const float*)d_in[0];
    const float* key   = (const float*)d_in[1];
    const float* value = (const float*)d_in[2];
    const float* mask  = (const float*)d_in[3];
    const float* Wq = (const float*)d_in[4];
    const float* bq = (const float*)d_in[5];
    const float* Wk = (const float*)d_in[6];
    const float* bk = (const float*)d_in[7];
    const float* Wv = (const float*)d_in[8];
    const float* bv = (const float*)d_in[9];
    const float* Wo = (const float*)d_in[10];
    const float* bo = (const float*)d_in[11];
    const float* scal = (const float*)d_in[12];

    char* ws = (char*)d_ws;
    f16* Wk16 = (f16*)(ws + 0);
    f16* Wv16 = (f16*)(ws + (1 << 17));
    f16* q16  = (f16*)(ws + (4 << 17));        // 512KB
    float* attnO = (float*)(ws + 1048576);     // 1MB
    f16* k16  = (f16*)(ws + 2097152);          // 32MB, [B,S,E]
    f16* v16T = (f16*)(ws + 35651584);         // 32MB, [B,E,S]
    float* partO = (float*)(ws + 69206016);    // 32MB
    float* partL = (float*)(ws + 103809024);   // 1MB

    cvt_w2_kernel<<<dim3(64, 2), 256, 0, stream>>>(Wk, Wv, Wk16, Wv16);

    const float qscale = 0.17677669529663687f * LOG2E; // 1/sqrt(32) * log2(e)
    proj_fused7<<<2304, 256, 0, stream>>>(query, key, value, Wq, Wk16, Wv16,
                                          bq, bk, bv, q16, k16, v16T, qscale);

    attn_kernel<<<256, 1024, 0, stream>>>(q16, k16, v16T, mask, scal, partO, partL);
    combine_kernel<<<1024, 256, 0, stream>>>(partO, partL, attnO);

    out_proj<<<dim3(32, 8), 256, 0, stream>>>(attnO, Wo, bo, (float*)d_out);
}